// Round 6
// baseline (201.026 us; speedup 1.0000x reference)
//
#include <hip/hip_runtime.h>
#include <hip/hip_bf16.h>

typedef __bf16 bf16x8 __attribute__((ext_vector_type(8)));
typedef float f32x4 __attribute__((ext_vector_type(4)));
typedef float f32x16 __attribute__((ext_vector_type(16)));
typedef int int32x8 __attribute__((ext_vector_type(8)));

#define N 8192
#define D 512
#define NS 64

// workspace layout (bytes) — ~21 MB
#define XS_OFF 0                            // fp8 X [N][512 B] plain K-major : 4 MB
#define WT_OFF (4 * 1024 * 1024)            // bf16 WT chunked [256][64s][32i] : 1 MB
#define SQ_OFF (WT_OFF + 1024 * 1024)       // f32 sq [N] : 32 KB
#define EP_OFF (SQ_OFF + 32 * 1024)         // f32 Ep [8 chunk][64 s][8192 n] : 16 MB
#define SC_OFF (EP_OFF + 8 * 64 * 8192 * 4) // f32 S1,S2 + int cnt

#define SCALE1 0x7F7F7F7F   // E8M0 = 127 -> 2^0 in every byte (unit scale)

// ---------------------------------------------------------------------------
// fused prep (blocks [0,2048): X -> fp8 plain row-major + sq;
//             [2048,2176): W -> chunked bf16 W^T)
__global__ __launch_bounds__(256) void prep(const float* __restrict__ X,
                                            const float* __restrict__ W,
                                            unsigned char* __restrict__ Xs,
                                            float* __restrict__ sq,
                                            __bf16* __restrict__ WTs,
                                            float* __restrict__ Sacc) {
    __shared__ float T[64][65];
    int t = threadIdx.x;
    if (blockIdx.x == 0 && t == 0) {        // zero loss accumulators + counter
        Sacc[0] = 0.f; Sacc[1] = 0.f; ((int*)Sacc)[2] = 0;
    }
    if (blockIdx.x < 2048) {
        int row = blockIdx.x * 4 + (t >> 6);
        int l = t & 63;
        const float* src = X + (size_t)row * D + l * 8;
        float4 v0 = *(const float4*)src;
        float4 v1 = *(const float4*)(src + 4);
        int w0 = __builtin_amdgcn_cvt_pk_fp8_f32(v0.x, v0.y, 0, false);
        w0     = __builtin_amdgcn_cvt_pk_fp8_f32(v0.z, v0.w, w0, true);
        int w1 = __builtin_amdgcn_cvt_pk_fp8_f32(v1.x, v1.y, 0, false);
        w1     = __builtin_amdgcn_cvt_pk_fp8_f32(v1.z, v1.w, w1, true);
        uint2 pk = make_uint2((unsigned)w0, (unsigned)w1);
        *(uint2*)(Xs + (size_t)row * 512 + l * 8) = pk;     // plain K-major
        float acc = v0.x*v0.x + v0.y*v0.y + v0.z*v0.z + v0.w*v0.w
                  + v1.x*v1.x + v1.y*v1.y + v1.z*v1.z + v1.w*v1.w;
        for (int off = 32; off > 0; off >>= 1) acc += __shfl_down(acc, off);
        if (l == 0) sq[row] = acc;
    } else {
        int i0 = (blockIdx.x - 2048) * 64;
        for (int j = 0; j < 16; ++j) {
            int idx = t + 256 * j;
            T[idx & 63][idx >> 6] = W[(size_t)(i0 + (idx >> 6)) * NS + (idx & 63)];
        }
        __syncthreads();
        for (int h = 0; h < 2; ++h)
            for (int j = 0; j < 8; ++j) {
                int idx = t + 256 * j;                  // 0..2047
                int s = idx >> 5, il = idx & 31;
                WTs[(size_t)((i0 >> 5) + h) * 2048 + idx] = (__bf16)T[s][h * 32 + il];
            }
    }
}

// ---------------------------------------------------------------------------
// main: grid (64 n-blocks, 8 i-chunks). Per block, 8 its of 128 i:
//  Gram 128x128 via MX-scaled fp8 mfma_scale_32x32x64 (unit scales; 2x rate,
//  8x fewer instrs). A/B frags are 32 contiguous K-major bytes per lane ->
//  loaded DIRECTLY from global with a 2-step register pipeline. K-loop has
//  NO LDS and NO barriers. LDS only holds KT (C->B layout transform) for the
//  bf16 16x16x32 E-phase. E partials stored per i-chunk (no atomics).
__global__ __launch_bounds__(256, 2) void kpca_main(
        const unsigned char* __restrict__ Xs, const __bf16* __restrict__ WTs,
        const float* __restrict__ sq, float* __restrict__ Ep) {
    __shared__ __align__(16) __bf16 KT[128 * 136];

    const int t = threadIdx.x;
    const int w = t >> 6, l = t & 63;
    const int quad = l >> 4, l15 = l & 15;
    const int l31 = l & 31, lh = l >> 5;        // 32x32 frag coords
    const int wm = w >> 1, wn = w & 1;
    const int n0 = blockIdx.x * 128;
    const int ic0 = blockIdx.y * 1024;

    // B-frag pointers (it-invariant): row n0+wn*64+nt*32+l31, bytes lh*32..+32
    const unsigned char* Bp0 = Xs + (size_t)(n0 + wn * 64 + l31) * 512 + lh * 32;
    const unsigned char* Bp1 = Bp0 + 32 * 512;
    const float sqn0 = sq[n0 + wn * 64 + l31];
    const float sqn1 = sq[n0 + wn * 64 + 32 + l31];

    f32x4 accE[4][2];
    for (int st = 0; st < 4; ++st)
        for (int n2 = 0; n2 < 2; ++n2)
            accE[st][n2] = (f32x4){0.f, 0.f, 0.f, 0.f};

    for (int it = 0; it < 8; ++it) {
        const int i0 = ic0 + it * 128;
        const unsigned char* Ap0 = Xs + (size_t)(i0 + wm * 64 + l31) * 512 + lh * 32;
        const unsigned char* Ap1 = Ap0 + 32 * 512;

        f32x16 accG[2][2];
        for (int mt = 0; mt < 2; ++mt)
            for (int nt = 0; nt < 2; ++nt)
                for (int r = 0; r < 16; ++r) accG[mt][nt][r] = 0.f;

        // register pipeline, depth 2 (K-step = 64 bytes)
        int32x8 a[2][2], b[2][2];
        a[0][0] = *(const int32x8*)(Ap0);      a[0][1] = *(const int32x8*)(Ap1);
        b[0][0] = *(const int32x8*)(Bp0);      b[0][1] = *(const int32x8*)(Bp1);
        a[1][0] = *(const int32x8*)(Ap0 + 64); a[1][1] = *(const int32x8*)(Ap1 + 64);
        b[1][0] = *(const int32x8*)(Bp0 + 64); b[1][1] = *(const int32x8*)(Bp1 + 64);

        #pragma unroll
        for (int kc = 0; kc < 8; ++kc) {
            const int cur = kc & 1;
            #pragma unroll
            for (int mt = 0; mt < 2; ++mt)
                #pragma unroll
                for (int nt = 0; nt < 2; ++nt)
                    accG[mt][nt] = __builtin_amdgcn_mfma_scale_f32_32x32x64_f8f6f4(
                        a[cur][mt], b[cur][nt], accG[mt][nt],
                        0, 0,                    // cbsz=fp8(e4m3), blgp=fp8
                        0, SCALE1, 0, SCALE1);   // unit scales
            if (kc < 6) {
                a[cur][0] = *(const int32x8*)(Ap0 + (kc + 2) * 64);
                a[cur][1] = *(const int32x8*)(Ap1 + (kc + 2) * 64);
                b[cur][0] = *(const int32x8*)(Bp0 + (kc + 2) * 64);
                b[cur][1] = *(const int32x8*)(Bp1 + (kc + 2) * 64);
            }
        }

        // ---- epilogue: d2 -> exp -> packed bf16 (accG dies here)
        // 32x32 C layout: col = l31 (n), row = (reg&3) + 8*(reg>>2) + 4*lh (i)
        uint2 pk[2][2][4];
        #pragma unroll
        for (int mt = 0; mt < 2; ++mt)
            #pragma unroll
            for (int rq = 0; rq < 4; ++rq) {
                const int ib = wm * 64 + mt * 32 + 8 * rq + 4 * lh;
                f32x4 si = *(const f32x4*)(sq + i0 + ib);
                #pragma unroll
                for (int nt = 0; nt < 2; ++nt) {
                    const float sn = nt ? sqn1 : sqn0;
                    union { __bf16 h[4]; uint2 u; } u;
                    #pragma unroll
                    for (int rr = 0; rr < 4; ++rr) {
                        float d2 = si[rr] + sn - 2.0f * accG[mt][nt][rq * 4 + rr];
                        u.h[rr] = (__bf16)__expf(d2 * -9.765625e-4f);  // exp(-d2/1024)
                    }
                    pk[mt][nt][rq] = u.u;
                }
            }

        // W^T frags for E-phase, first half (kc2 0,1) — global, L2-hot
        const __bf16* wslab = WTs + (size_t)(i0 >> 5) * 2048;
        bf16x8 aw[2][4];
        #pragma unroll
        for (int kc2 = 0; kc2 < 2; ++kc2)
            for (int st = 0; st < 4; ++st)
                aw[kc2][st] = *(const bf16x8*)(wslab + kc2 * 2048 +
                                               (st * 16 + l15) * 32 + quad * 8);

        __syncthreads();   // prev it's E-phase KT reads complete
        #pragma unroll
        for (int mt = 0; mt < 2; ++mt)
            for (int nt = 0; nt < 2; ++nt)
                for (int rq = 0; rq < 4; ++rq) {
                    const int nloc = wn * 64 + nt * 32 + l31;
                    const int ib = wm * 64 + mt * 32 + 8 * rq + 4 * lh;
                    *(uint2*)(KT + nloc * 136 + ib) = pk[mt][nt][rq];
                }
        __syncthreads();   // KT visible

        // E[s][n] += sum_i WT[s][i] * KT[n][i]; wave w owns n in [w*32,+32)
        #pragma unroll
        for (int kc2 = 0; kc2 < 2; ++kc2) {
            bf16x8 bk[2];
            for (int n2 = 0; n2 < 2; ++n2)
                bk[n2] = *(const bf16x8*)(KT + (w * 32 + n2 * 16 + l15) * 136 +
                                          kc2 * 32 + quad * 8);
            #pragma unroll
            for (int st = 0; st < 4; ++st)
                for (int n2 = 0; n2 < 2; ++n2)
                    accE[st][n2] = __builtin_amdgcn_mfma_f32_16x16x32_bf16(
                        aw[kc2][st], bk[n2], accE[st][n2], 0, 0, 0);
        }
        #pragma unroll
        for (int kc2 = 0; kc2 < 2; ++kc2)      // second half (kc2 2,3)
            for (int st = 0; st < 4; ++st)
                aw[kc2][st] = *(const bf16x8*)(wslab + (kc2 + 2) * 2048 +
                                               (st * 16 + l15) * 32 + quad * 8);
        #pragma unroll
        for (int kc2 = 0; kc2 < 2; ++kc2) {
            bf16x8 bk[2];
            for (int n2 = 0; n2 < 2; ++n2)
                bk[n2] = *(const bf16x8*)(KT + (w * 32 + n2 * 16 + l15) * 136 +
                                          (kc2 + 2) * 32 + quad * 8);
            #pragma unroll
            for (int st = 0; st < 4; ++st)
                for (int n2 = 0; n2 < 2; ++n2)
                    accE[st][n2] = __builtin_amdgcn_mfma_f32_16x16x32_bf16(
                        aw[kc2][st], bk[n2], accE[st][n2], 0, 0, 0);
        }
    }

    // ---- per-chunk E partial: plain stores
    float* ep = Ep + (size_t)blockIdx.y * (NS * N);
    #pragma unroll
    for (int st = 0; st < 4; ++st)
        for (int n2 = 0; n2 < 2; ++n2)
            for (int r = 0; r < 4; ++r) {
                int s = st * 16 + quad * 4 + r;
                int n = n0 + w * 32 + n2 * 16 + l15;
                ep[(size_t)s * N + n] = accE[st][n2][r];
            }
}

// ---------------------------------------------------------------------------
// loss: 256 blocks = 64 s x 4 n-chunks; sums the 8 E partials, reduces;
// last block finalizes the scalar.
__global__ __launch_bounds__(256) void loss_kernel(const float* __restrict__ Ep,
                                                   const __bf16* __restrict__ WTs,
                                                   const float* __restrict__ lam,
                                                   float* __restrict__ Sacc,
                                                   float* __restrict__ out) {
    int s = blockIdx.x >> 2;
    int nb = (blockIdx.x & 3) * 2048;
    int t = threadIdx.x;
    float a1 = 0.f, a2 = 0.f;
    for (int j = 0; j < 8; ++j) {
        int n = nb + t + j * 256;
        float e = 0.f;
        #pragma unroll
        for (int c = 0; c < 8; ++c)
            e += Ep[(size_t)c * (NS * N) + (size_t)s * N + n];
        a1 += e * e;
        a2 += e * (float)WTs[(size_t)(n >> 5) * 2048 + s * 32 + (n & 31)];
    }
    for (int off = 32; off > 0; off >>= 1) {
        a1 += __shfl_down(a1, off);
        a2 += __shfl_down(a2, off);
    }
    __shared__ float r1[4], r2[4];
    int wv = t >> 6, ln = t & 63;
    if (ln == 0) { r1[wv] = a1; r2[wv] = a2; }
    __syncthreads();
    if (t == 0) {
        atomicAdd(Sacc + 0, lam[s] * (r1[0] + r1[1] + r1[2] + r1[3]));
        atomicAdd(Sacc + 1, r2[0] + r2[1] + r2[2] + r2[3]);
        __threadfence();
        int prev = atomicAdd((int*)Sacc + 2, 1);
        if (prev == 255) {                       // last block finalizes
            __threadfence();
            volatile float* vs = (volatile float*)Sacc;
            float L = 0.5f * (vs[1] - vs[0]);    // loss1=-S1/2, loss2=S2/2
            out[0] = L + 0.05f * L * L;          // C_STAB/2 = 0.05
        }
    }
}

// ---------------------------------------------------------------------------
extern "C" void kernel_launch(void* const* d_in, const int* in_sizes, int n_in,
                              void* d_out, int out_size, void* d_ws, size_t ws_size,
                              hipStream_t stream) {
    const float* X   = (const float*)d_in[0];   // [8192][512]
    const float* W   = (const float*)d_in[1];   // [8192][64]
    const float* lam = (const float*)d_in[2];   // [64]
    float* out = (float*)d_out;
    char* ws = (char*)d_ws;
    unsigned char* Xs = (unsigned char*)(ws + XS_OFF);
    __bf16* WTs = (__bf16*)(ws + WT_OFF);
    float* sq   = (float*)(ws + SQ_OFF);
    float* Ep   = (float*)(ws + EP_OFF);
    float* Sacc = (float*)(ws + SC_OFF);

    prep<<<2048 + 128, 256, 0, stream>>>(X, W, Xs, sq, WTs, Sacc);
    kpca_main<<<dim3(64, 8), 256, 0, stream>>>(Xs, WTs, sq, Ep);
    loss_kernel<<<256, 256, 0, stream>>>(Ep, WTs, lam, Sacc, out);
}